// Round 7
// baseline (504.846 us; speedup 1.0000x reference)
//
#include <hip/hip_runtime.h>
#include <hip/hip_bf16.h>

// Head-axis-softmax SDPA, B=2 S=2048 N=16 D=64, fp32 in/out.
// softmax over HEADS (n) -> local per (b,q,k).
//
// R7: FUSED single pass. Block = 4 waves; wave w owns heads 4w..4w+3 of one
// 32q x 32k tile. All MFMA C-tiles share the same lane<->(q,k) mapping, so the
// cross-head denominator is: per-lane register adds over each wave's 4 heads,
// + a tiny 4-slot LDS combine (wave0). Only 2 barriers per k-iter, QK computed
// ONCE (unlike R5/R6 two-pass), no 16-wave monolith coupling (unlike R2/R4).
//   per k-iter/wave: 4x(QK 4-MFMA -> exp -> bf16 scatter to private pw tile),
//   slot write (4xb128) | barrier | wave0: sum slots + mask -> rd bf16 tile |
//   barrier | rd A-frags (shared by 4 heads), per head: e A-read * rd -> PV.
// Inputs repacked (R4 cvt kernels): Qb,Kb=[b,n,s,d] bf16, Vt=[b,n,d,s] bf16.
// ws need = 25.2 MB (proven >=32.9 MB available since R5/R6 ran this branch).

#define B_ 2
#define S_ 2048
#define N_ 16
#define D_ 64
#define TQ 32
#define TK 32
#define KSPLIT 4
#define KITERS (S_ / TK / KSPLIT)  // 16

#define PK 40   // pw row stride (bf16): 80 B, 16B-aligned
#define SLP 20  // slot per-lane stride (f32): 80 B, 16B-aligned, 4-way max

typedef __bf16 bf16x4 __attribute__((ext_vector_type(4)));
typedef __bf16 bf16x8 __attribute__((ext_vector_type(8)));
typedef float  f32x16 __attribute__((ext_vector_type(16)));

// ---------------------------------------------------------------------------
// Pre-pass 1: Q,K [b,s,n,d] f32 -> [b,n,s,d] bf16.
// ---------------------------------------------------------------------------
__global__ __launch_bounds__(256) void cvt_qk_kernel(
    const float* __restrict__ Qf, const float* __restrict__ Kf,
    __bf16* __restrict__ Qb, __bf16* __restrict__ Kb)
{
    const int z = blockIdx.z;
    const float* src = (z < B_) ? Qf : Kf;
    __bf16*      dst = (z < B_) ? Qb : Kb;
    const int b = (z < B_) ? z : z - B_;
    const int n = blockIdx.y;
    const int t = threadIdx.x;
    const int d4 = (t & 15) * 4;
    const int s  = blockIdx.x * 16 + (t >> 4);

    const float4 v = *(const float4*)&src[(((size_t)b * S_ + s) * N_ + n) * D_ + d4];
    bf16x4 o;
    o[0] = (__bf16)v.x; o[1] = (__bf16)v.y; o[2] = (__bf16)v.z; o[3] = (__bf16)v.w;
    *(bf16x4*)&dst[(((size_t)b * N_ + n) * S_ + s) * D_ + d4] = o;
}

// ---------------------------------------------------------------------------
// Pre-pass 2: V [b,s,n,d] f32 -> [b,n,d,s] bf16 (transpose via LDS).
// ---------------------------------------------------------------------------
__global__ __launch_bounds__(256) void cvt_v_kernel(
    const float* __restrict__ V, __bf16* __restrict__ Vt)
{
    __shared__ __bf16 tile[64][68];
    const int s0 = blockIdx.x * 64;
    const int n  = blockIdx.y;
    const int b  = blockIdx.z;
    const int t  = threadIdx.x;

    {
        const int d4 = (t & 15) * 4;
        const int sr = t >> 4;
        #pragma unroll
        for (int r = 0; r < 4; ++r) {
            const int s = sr + r * 16;
            const float4 v = *(const float4*)&V[(((size_t)b * S_ + s0 + s) * N_ + n) * D_ + d4];
            tile[s][d4 + 0] = (__bf16)v.x;
            tile[s][d4 + 1] = (__bf16)v.y;
            tile[s][d4 + 2] = (__bf16)v.z;
            tile[s][d4 + 3] = (__bf16)v.w;
        }
    }
    __syncthreads();
    {
        const int s4 = (t & 15) * 4;
        const int dr = t >> 4;
        #pragma unroll
        for (int r = 0; r < 4; ++r) {
            const int d = dr + r * 16;
            bf16x4 o;
            o[0] = tile[s4 + 0][d];
            o[1] = tile[s4 + 1][d];
            o[2] = tile[s4 + 2][d];
            o[3] = tile[s4 + 3][d];
            *(bf16x4*)&Vt[(((size_t)b * N_ + n) * D_ + d) * S_ + s0 + s4] = o;
        }
    }
}

// ---------------------------------------------------------------------------
// Fused kernel.
// ---------------------------------------------------------------------------
__global__ __launch_bounds__(256, 2) void fused_kernel(
    const __bf16* __restrict__ Qb, const __bf16* __restrict__ Kb,
    const __bf16* __restrict__ Vt, const int* __restrict__ M,
    float* __restrict__ O)
{
    // 40960 + 20480 + 2560 = 64000 B (<= 64 KB; 2 blocks/CU within 160 KB)
    __shared__ __align__(16) __bf16 pw[N_][TQ][PK];    // per-head e tiles (wave-private)
    __shared__ __align__(16) float  slot[4][64][SLP];  // per-wave denom partials
    __shared__ __align__(16) __bf16 rdt[TQ][PK];       // rd tile, [q][k] bf16

    const int tid  = threadIdx.x;
    const int w    = tid >> 6;
    const int lane = tid & 63;
    const int lo   = lane & 31;
    const int hi   = lane >> 5;

    const int q0 = blockIdx.x * TQ;
    const int kz = blockIdx.y;
    const int b  = blockIdx.z;

    f32x16 oacc[4][2] = {};   // 4 heads x (d 0..31 | 32..63), 128 AGPR

    for (int it = 0; it < KITERS; ++it) {
        const int k0 = (kz * KITERS + it) * TK;

        // ---- phase 1: per head QK + exp; denom accumulates in registers
        f32x16 sumv = {};
        #pragma unroll
        for (int h = 0; h < 4; ++h) {
            const int n = w * 4 + h;
            const __bf16* Qh = Qb + (((size_t)b * N_ + n) * S_ + q0 + lo) * D_ + hi * 8;
            const __bf16* Kh = Kb + (((size_t)b * N_ + n) * S_ + k0 + lo) * D_ + hi * 8;
            f32x16 s = {};
            #pragma unroll
            for (int c = 0; c < 4; ++c) {
                bf16x8 qf = *(const bf16x8*)(Qh + c * 16);
                bf16x8 kf = *(const bf16x8*)(Kh + c * 16);
                s = __builtin_amdgcn_mfma_f32_32x32x16_bf16(qf, kf, s, 0, 0, 0);
            }
            #pragma unroll
            for (int r = 0; r < 16; ++r) {
                const float e = __expf(s[r] * 0.125f);
                sumv[r] += e;
                pw[n][(r & 3) + 8 * (r >> 2) + 4 * hi][lo] = (__bf16)e;  // C scatter, 2-way free
            }
        }
        #pragma unroll
        for (int c = 0; c < 4; ++c) {
            float4 v4 = { sumv[4*c], sumv[4*c+1], sumv[4*c+2], sumv[4*c+3] };
            *(float4*)&slot[w][lane][4 * c] = v4;
        }

        __syncthreads();  // barrier 1: partials visible

        // ---- phase 2 (wave 0 only): total denom + mask -> rd tile
        if (w == 0) {
            float tot[16];
            #pragma unroll
            for (int c = 0; c < 4; ++c) {
                float4 a0 = *(const float4*)&slot[0][lane][4 * c];
                float4 a1 = *(const float4*)&slot[1][lane][4 * c];
                float4 a2 = *(const float4*)&slot[2][lane][4 * c];
                float4 a3 = *(const float4*)&slot[3][lane][4 * c];
                tot[4*c+0] = a0.x + a1.x + a2.x + a3.x;
                tot[4*c+1] = a0.y + a1.y + a2.y + a3.y;
                tot[4*c+2] = a0.z + a1.z + a2.z + a3.z;
                tot[4*c+3] = a0.w + a1.w + a2.w + a3.w;
            }
            #pragma unroll
            for (int r = 0; r < 16; ++r) {
                const int row = (r & 3) + 8 * (r >> 2) + 4 * hi;
                const int m = M[(size_t)b * S_ * S_ + (size_t)(q0 + row) * S_ + (k0 + lo)];
                // mask==0: ref softmax over all-(-inf) heads -> NaN weights
                rdt[row][lo] = (__bf16)(m ? (1.0f / tot[r]) : __builtin_nanf(""));
            }
        }

        __syncthreads();  // barrier 2: rd visible

        // ---- phase 3: per head PV (wave-local; no barriers)
        // rd A-frags read ONCE, shared by this wave's 4 heads
        bf16x8 rda[2];
        #pragma unroll
        for (int ks = 0; ks < 2; ++ks)
            rda[ks] = *(const bf16x8*)&rdt[lo][ks * 16 + hi * 8];

        #pragma unroll
        for (int h = 0; h < 4; ++h) {
            const int n = w * 4 + h;
            const __bf16* Vh = Vt + ((size_t)b * N_ + n) * D_ * S_;
            #pragma unroll
            for (int ks = 0; ks < 2; ++ks) {
                bf16x8 vf0 = *(const bf16x8*)&Vh[(size_t)(lo) * S_      + k0 + ks * 16 + hi * 8];
                bf16x8 vf1 = *(const bf16x8*)&Vh[(size_t)(32 + lo) * S_ + k0 + ks * 16 + hi * 8];
                bf16x8 ef  = *(const bf16x8*)&pw[n][lo][ks * 16 + hi * 8];
                bf16x8 wf;
                #pragma unroll
                for (int j = 0; j < 8; ++j)
                    wf[j] = (__bf16)((float)ef[j] * (float)rda[ks][j]);
                oacc[h][0] = __builtin_amdgcn_mfma_f32_32x32x16_bf16(wf, vf0, oacc[h][0], 0, 0, 0);
                oacc[h][1] = __builtin_amdgcn_mfma_f32_32x32x16_bf16(wf, vf1, oacc[h][1], 0, 0, 0);
            }
        }
        // no 3rd barrier needed: next iter's pw/slot writes are by the owning
        // wave (program order), and wave0's next rdt write is gated by the
        // next barrier 1, which every wave reaches only after its rdt reads.
    }

    // ---- epilogue: KSPLIT partials combine via device atomics (O pre-zeroed)
    #pragma unroll
    for (int h = 0; h < 4; ++h) {
        const int n = w * 4 + h;
        #pragma unroll
        for (int r = 0; r < 16; ++r) {
            const int row = (r & 3) + 8 * (r >> 2) + 4 * hi;
            const size_t base = (((size_t)b * N_ + n) * S_ + (q0 + row)) * (size_t)D_;
            atomicAdd(&O[base + lo],      oacc[h][0][r]);
            atomicAdd(&O[base + 32 + lo], oacc[h][1][r]);
        }
    }
}

extern "C" void kernel_launch(void* const* d_in, const int* in_sizes, int n_in,
                              void* d_out, int out_size, void* d_ws, size_t ws_size,
                              hipStream_t stream) {
    const float* Q = (const float*)d_in[0];
    const float* K = (const float*)d_in[1];
    const float* V = (const float*)d_in[2];
    const int*   M = (const int*)d_in[3];
    float* O = (float*)d_out;

    hipMemsetAsync(d_out, 0, (size_t)out_size * sizeof(float), stream);

    const size_t per = (size_t)B_ * N_ * S_ * D_;   // 4.19 M elems; 3 bufs = 25.2 MB
    __bf16* Qb = (__bf16*)d_ws;                      // ws proven >= 32.9 MB (R5/R6)
    __bf16* Kb = Qb + per;
    __bf16* Vt = Kb + per;

    cvt_qk_kernel<<<dim3(S_ / 16, N_, B_ * 2), dim3(256), 0, stream>>>(Q, K, Qb, Kb);
    cvt_v_kernel<<<dim3(S_ / 64, N_, B_), dim3(256), 0, stream>>>(V, Vt);
    fused_kernel<<<dim3(S_ / TQ, KSPLIT, B_), dim3(256), 0, stream>>>(Qb, Kb, Vt, M, O);
}

// Round 8
// 416.007 us; speedup vs baseline: 1.2136x; 1.2136x over previous
//
#include <hip/hip_runtime.h>
#include <hip/hip_bf16.h>

// Head-axis-softmax SDPA, B=2 S=2048 N=16 D=64, fp32 in/out.
// softmax over HEADS (n) -> local per (b,q,k).
//
// R8: fused single pass (R7 structure) with HALVED register footprint.
// R7 spilled: 128-reg oacc + ~120 arch hit the 256-reg cap of
// __launch_bounds__(256,2) -> per-iter scratch traffic (~80MB excess
// FETCH+WRITE). Fix: 16x16x32 MFMA, TQ=16 -> oacc = 64 regs, peak ~175.
// Block = 4 waves x 4 heads = all 16 heads (required by cross-head softmax).
// Cross-head denom: per-lane register adds (own 4 heads) + 4-slot LDS combine.
// slot uses odd stride 9 (bank walk period 32 -> conflict-free), fixing R7's
// 3.1M-cycle stride-20 float4 conflicts.
//
// mfma_f32_16x16x32_bf16 layouts (verified m89/m120):
//   A: m=lane&15, k=(lane>>4)*8+j     B: col=lane&15, k=(lane>>4)*8+j
//   C/D: col=lane&15, row=(lane>>4)*4+reg

#define B_ 2
#define S_ 2048
#define N_ 16
#define D_ 64
#define TQ 16
#define TK 32
#define KSPLIT 2
#define KITERS (S_ / TK / KSPLIT)  // 32

#define PK 40   // pw/rdt key-stride (bf16): 80 B, 16B-aligned
#define SLW 9   // slot per-lane stride (f32 words): odd -> conflict-free

typedef __bf16 bf16x4 __attribute__((ext_vector_type(4)));
typedef __bf16 bf16x8 __attribute__((ext_vector_type(8)));
typedef float  f32x4  __attribute__((ext_vector_type(4)));

// ---------------------------------------------------------------------------
// Pre-pass 1: Q,K [b,s,n,d] f32 -> [b,n,s,d] bf16.
// ---------------------------------------------------------------------------
__global__ __launch_bounds__(256) void cvt_qk_kernel(
    const float* __restrict__ Qf, const float* __restrict__ Kf,
    __bf16* __restrict__ Qb, __bf16* __restrict__ Kb)
{
    const int z = blockIdx.z;
    const float* src = (z < B_) ? Qf : Kf;
    __bf16*      dst = (z < B_) ? Qb : Kb;
    const int b = (z < B_) ? z : z - B_;
    const int n = blockIdx.y;
    const int t = threadIdx.x;
    const int d4 = (t & 15) * 4;
    const int s  = blockIdx.x * 16 + (t >> 4);

    const float4 v = *(const float4*)&src[(((size_t)b * S_ + s) * N_ + n) * D_ + d4];
    bf16x4 o;
    o[0] = (__bf16)v.x; o[1] = (__bf16)v.y; o[2] = (__bf16)v.z; o[3] = (__bf16)v.w;
    *(bf16x4*)&dst[(((size_t)b * N_ + n) * S_ + s) * D_ + d4] = o;
}

// ---------------------------------------------------------------------------
// Pre-pass 2: V [b,s,n,d] f32 -> [b,n,d,s] bf16 (transpose via LDS).
// ---------------------------------------------------------------------------
__global__ __launch_bounds__(256) void cvt_v_kernel(
    const float* __restrict__ V, __bf16* __restrict__ Vt)
{
    __shared__ __bf16 tile[64][68];
    const int s0 = blockIdx.x * 64;
    const int n  = blockIdx.y;
    const int b  = blockIdx.z;
    const int t  = threadIdx.x;

    {
        const int d4 = (t & 15) * 4;
        const int sr = t >> 4;
        #pragma unroll
        for (int r = 0; r < 4; ++r) {
            const int s = sr + r * 16;
            const float4 v = *(const float4*)&V[(((size_t)b * S_ + s0 + s) * N_ + n) * D_ + d4];
            tile[s][d4 + 0] = (__bf16)v.x;
            tile[s][d4 + 1] = (__bf16)v.y;
            tile[s][d4 + 2] = (__bf16)v.z;
            tile[s][d4 + 3] = (__bf16)v.w;
        }
    }
    __syncthreads();
    {
        const int s4 = (t & 15) * 4;
        const int dr = t >> 4;
        #pragma unroll
        for (int r = 0; r < 4; ++r) {
            const int d = dr + r * 16;
            bf16x4 o;
            o[0] = tile[s4 + 0][d];
            o[1] = tile[s4 + 1][d];
            o[2] = tile[s4 + 2][d];
            o[3] = tile[s4 + 3][d];
            *(bf16x4*)&Vt[(((size_t)b * N_ + n) * D_ + d) * S_ + s0 + s4] = o;
        }
    }
}

// ---------------------------------------------------------------------------
// Fused kernel: 4 waves x 4 heads, TQ=16, TK=32, 16x16x32 MFMA.
// ---------------------------------------------------------------------------
__global__ __launch_bounds__(256, 2) void fused_kernel(
    const __bf16* __restrict__ Qb, const __bf16* __restrict__ Kb,
    const __bf16* __restrict__ Vt, const int* __restrict__ M,
    float* __restrict__ O)
{
    // 20480 + 9216 + 1280 = 30976 B -> LDS allows >=4 blocks/CU; regs decide.
    __shared__ __align__(16) __bf16 pw[N_][TQ][PK];    // per-head e tiles [q][key]
    __shared__            float  slot[4][64][SLW];     // per-wave denom partials
    __shared__ __align__(16) __bf16 rdt[TQ][PK];       // rd tile [q][key]

    const int tid  = threadIdx.x;
    const int w    = tid >> 6;
    const int lane = tid & 63;
    const int col  = lane & 15;   // A.m / B.col / C.col
    const int quad = lane >> 4;   // 0..3

    const int q0 = blockIdx.x * TQ;
    const int kz = blockIdx.y;
    const int b  = blockIdx.z;

    f32x4 oacc[4][4] = {};   // [head][d-tile 16] = 64 unified regs

    for (int it = 0; it < KITERS; ++it) {
        const int k0 = (kz * KITERS + it) * TK;

        // ---- phase 1: QK + exp per head; cross-head denom in registers.
        // Two 16-key subtiles (sk=0,1) cover TK=32.
        float sumv[8];                       // [sk*4 + r]
        #pragma unroll
        for (int i = 0; i < 8; ++i) sumv[i] = 0.0f;

        #pragma unroll
        for (int h = 0; h < 4; ++h) {
            const int n = w * 4 + h;
            const __bf16* Qh = Qb + (((size_t)b * N_ + n) * S_ + q0 + col) * D_ + quad * 8;
            const __bf16* Kh = Kb + (((size_t)b * N_ + n) * S_ + k0 + col) * D_ + quad * 8;
            f32x4 s0 = {}, s1 = {};
            #pragma unroll
            for (int c = 0; c < 2; ++c) {
                bf16x8 qf  = *(const bf16x8*)(Qh + c * 32);
                bf16x8 kf0 = *(const bf16x8*)(Kh + c * 32);
                bf16x8 kf1 = *(const bf16x8*)(Kh + (size_t)16 * D_ + c * 32);
                s0 = __builtin_amdgcn_mfma_f32_16x16x32_bf16(qf, kf0, s0, 0, 0, 0);
                s1 = __builtin_amdgcn_mfma_f32_16x16x32_bf16(qf, kf1, s1, 0, 0, 0);
            }
            #pragma unroll
            for (int r = 0; r < 4; ++r) {
                const int row = quad * 4 + r;
                const float e0 = __expf(s0[r] * 0.125f);
                const float e1 = __expf(s1[r] * 0.125f);
                sumv[r]     += e0;
                sumv[4 + r] += e1;
                pw[n][row][col]      = (__bf16)e0;   // C scatter: 2-way, free
                pw[n][row][16 + col] = (__bf16)e1;
            }
        }
        #pragma unroll
        for (int i = 0; i < 8; ++i) slot[w][lane][i] = sumv[i];   // stride-9: conflict-free

        __syncthreads();  // barrier 1: partials visible

        // ---- phase 2 (wave 0): total denom + mask -> rd tile
        if (w == 0) {
            #pragma unroll
            for (int sk = 0; sk < 2; ++sk) {
                #pragma unroll
                for (int r = 0; r < 4; ++r) {
                    const int i = sk * 4 + r;
                    const float tot = slot[0][lane][i] + slot[1][lane][i]
                                    + slot[2][lane][i] + slot[3][lane][i];
                    const int row = quad * 4 + r;
                    const int kk  = k0 + sk * 16 + col;
                    const int m = M[(size_t)b * S_ * S_ + (size_t)(q0 + row) * S_ + kk];
                    // mask==0: ref softmax over all-(-inf) heads -> NaN weights
                    rdt[row][sk * 16 + col] = (__bf16)(m ? (1.0f / tot) : __builtin_nanf(""));
                }
            }
        }

        __syncthreads();  // barrier 2: rd visible

        // ---- phase 3: per head PV (wave-local, no barriers)
        // A-frag rd, read once, shared by this wave's 4 heads: rd[q=col][key=quad*8+j]
        bf16x8 rda = *(const bf16x8*)&rdt[col][quad * 8];

        #pragma unroll
        for (int h = 0; h < 4; ++h) {
            const int n = w * 4 + h;
            bf16x8 ef = *(const bf16x8*)&pw[n][col][quad * 8];
            bf16x8 wf;
            #pragma unroll
            for (int j = 0; j < 8; ++j)
                wf[j] = (__bf16)((float)ef[j] * (float)rda[j]);
            const __bf16* Vh = Vt + ((size_t)b * N_ + n) * D_ * S_;
            #pragma unroll
            for (int dt = 0; dt < 4; ++dt) {
                bf16x8 vf = *(const bf16x8*)&Vh[(size_t)(dt * 16 + col) * S_ + k0 + quad * 8];
                oacc[h][dt] = __builtin_amdgcn_mfma_f32_16x16x32_bf16(wf, vf, oacc[h][dt], 0, 0, 0);
            }
        }
        // no 3rd barrier: pw/slot are rewritten only by their owning wave
        // (program order), and wave0's next rdt write is gated by barrier 1
        // of it+1, which each wave reaches only after its rdt reads here.
    }

    // ---- epilogue: KSPLIT partials combine via device atomics (O pre-zeroed)
    #pragma unroll
    for (int h = 0; h < 4; ++h) {
        const int n = w * 4 + h;
        #pragma unroll
        for (int r = 0; r < 4; ++r) {
            const int row = quad * 4 + r;
            const size_t base = (((size_t)b * N_ + n) * S_ + (q0 + row)) * (size_t)D_;
            #pragma unroll
            for (int dt = 0; dt < 4; ++dt)
                atomicAdd(&O[base + dt * 16 + col], oacc[h][dt][r]);
        }
    }
}

extern "C" void kernel_launch(void* const* d_in, const int* in_sizes, int n_in,
                              void* d_out, int out_size, void* d_ws, size_t ws_size,
                              hipStream_t stream) {
    const float* Q = (const float*)d_in[0];
    const float* K = (const float*)d_in[1];
    const float* V = (const float*)d_in[2];
    const int*   M = (const int*)d_in[3];
    float* O = (float*)d_out;

    hipMemsetAsync(d_out, 0, (size_t)out_size * sizeof(float), stream);

    const size_t per = (size_t)B_ * N_ * S_ * D_;   // 4.19 M elems; 3 bufs = 25.2 MB
    __bf16* Qb = (__bf16*)d_ws;                      // ws proven >= 32.9 MB (R5/R6)
    __bf16* Kb = Qb + per;
    __bf16* Vt = Kb + per;

    cvt_qk_kernel<<<dim3(S_ / 16, N_, B_ * 2), dim3(256), 0, stream>>>(Q, K, Qb, Kb);
    cvt_v_kernel<<<dim3(S_ / 64, N_, B_), dim3(256), 0, stream>>>(V, Vt);
    fused_kernel<<<dim3(S_ / TQ, KSPLIT, B_), dim3(256), 0, stream>>>(Qb, Kb, Vt, M, O);
}